// Round 8
// baseline (811.566 us; speedup 1.0000x reference)
//
#include <hip/hip_runtime.h>
#include <hip/hip_bf16.h>

#define DM   2048
#define LSEQ 2048
#define NB   2
#define NH   16
#define HDIM 128
#define DFF  8192

typedef __attribute__((ext_vector_type(8))) short bf16x8;
typedef __attribute__((ext_vector_type(4))) float f32x4;

typedef __attribute__((address_space(1))) void gvoid;
typedef __attribute__((address_space(3))) void lvoid;
#define GLDS16(g, s) __builtin_amdgcn_global_load_lds((const gvoid*)(g), (lvoid*)(s), 16, 0, 0)

__device__ __forceinline__ unsigned short f2b(float f) {
    __hip_bfloat16 h = __float2bfloat16(f);
    return *reinterpret_cast<unsigned short*>(&h);
}

// ---------------- transpose + fp32->bf16 convert: in[R][C] f32 -> out[C][R] bf16
__global__ __launch_bounds__(256) void transpose_bf16(const float* __restrict__ in,
                                                      unsigned short* __restrict__ out,
                                                      int R, int C) {
    __shared__ float t[32][33];
    const int c0 = blockIdx.x * 32, r0 = blockIdx.y * 32;
    const int tx = threadIdx.x, ty = threadIdx.y;  // block (32,8)
#pragma unroll
    for (int i = 0; i < 4; i++)
        t[ty + 8 * i][tx] = in[(size_t)(r0 + ty + 8 * i) * C + c0 + tx];
    __syncthreads();
#pragma unroll
    for (int i = 0; i < 4; i++)
        out[(size_t)(c0 + ty + 8 * i) * R + r0 + tx] = f2b(t[tx][ty + 8 * i]);
}

// ---------------- LayerNorm: x[row][2048] f32 -> out bf16
__global__ __launch_bounds__(256) void ln_k(const float* __restrict__ x,
                                            const float* __restrict__ g,
                                            const float* __restrict__ bta,
                                            unsigned short* __restrict__ out) {
    const int row = blockIdx.x, tid = threadIdx.x;
    const float* xr = x + (size_t)row * DM;
    float4 v0 = *(const float4*)&xr[tid * 4];
    float4 v1 = *(const float4*)&xr[1024 + tid * 4];
    float s  = v0.x + v0.y + v0.z + v0.w + v1.x + v1.y + v1.z + v1.w;
    float ss = v0.x * v0.x + v0.y * v0.y + v0.z * v0.z + v0.w * v0.w
             + v1.x * v1.x + v1.y * v1.y + v1.z * v1.z + v1.w * v1.w;
#pragma unroll
    for (int o = 32; o; o >>= 1) { s += __shfl_down(s, o); ss += __shfl_down(ss, o); }
    __shared__ float red[8];
    const int w = tid >> 6, l = tid & 63;
    if (l == 0) { red[w] = s; red[4 + w] = ss; }
    __syncthreads();
    s  = red[0] + red[1] + red[2] + red[3];
    ss = red[4] + red[5] + red[6] + red[7];
    const float mu  = s * (1.0f / DM);
    const float var = ss * (1.0f / DM) - mu * mu;
    const float rst = rsqrtf(var + 1e-5f);
    float4 g0 = *(const float4*)&g[tid * 4];
    float4 b0 = *(const float4*)&bta[tid * 4];
    float4 g1 = *(const float4*)&g[1024 + tid * 4];
    float4 b1 = *(const float4*)&bta[1024 + tid * 4];
    ushort4 o0, o1;
    o0.x = f2b((v0.x - mu) * rst * g0.x + b0.x);
    o0.y = f2b((v0.y - mu) * rst * g0.y + b0.y);
    o0.z = f2b((v0.z - mu) * rst * g0.z + b0.z);
    o0.w = f2b((v0.w - mu) * rst * g0.w + b0.w);
    o1.x = f2b((v1.x - mu) * rst * g1.x + b1.x);
    o1.y = f2b((v1.y - mu) * rst * g1.y + b1.y);
    o1.z = f2b((v1.z - mu) * rst * g1.z + b1.z);
    o1.w = f2b((v1.w - mu) * rst * g1.w + b1.w);
    *(ushort4*)&out[(size_t)row * DM + tid * 4] = o0;
    *(ushort4*)&out[(size_t)row * DM + 1024 + tid * 4] = o1;
}

// ---------------- m97-style GEMM (WO, MLP2; both launched at grid (16,32))
// ROUND-8: XCD column-major remap (same mechanism as gemm8's round-6 remap):
// resident 32 blocks/XCD = 4 m-rows x 8 n-cols -> per-K-step B slice 64 KB
// (L2-resident) instead of 16 distinct B panels. MLP2 was fetch-bound (380 MB).
template <bool BIAS, bool GELU_, bool RES, bool OUTBF>
__global__ __launch_bounds__(256) void gemm_k(const unsigned short* __restrict__ A,
                                              const unsigned short* __restrict__ Bt,
                                              const float* __restrict__ bias,
                                              const float* __restrict__ res,
                                              void* __restrict__ outp,
                                              int M, int N, int K) {
    __shared__ unsigned short Al[128 * 32];
    __shared__ unsigned short Bl[128 * 32];
    const int tid = threadIdx.x, w = tid >> 6, l = tid & 63;
    int bx = blockIdx.x, by = blockIdx.y;
    if (gridDim.x == 16 && gridDim.y == 32) {  // WO / MLP2 shape
        const int flat = by * 16 + bx;         // dispatch order (x fastest)
        const int xx = flat & 7, jj = flat >> 3;
        by = 4 * xx + (jj & 3);                // m-row
        bx = jj >> 2;                          // n-col
    }
    const int n0 = bx * 128, m0 = by * 128;
    const int wr = (w >> 1) * 64, wc = (w & 1) * 64;
    const int lr = l & 15, ko = (l >> 4) * 8;
    f32x4 acc[4][4] = {};

    const int srow = w * 32 + (l >> 2);
    const int skk  = (l & 3) * 8;
    const unsigned short* ga0 = A + (size_t)(m0 + srow) * K + skk;
    const unsigned short* ga1 = ga0 + (size_t)16 * K;
    const unsigned short* gb0 = Bt + (size_t)(n0 + srow) * K + skk;
    const unsigned short* gb1 = gb0 + (size_t)16 * K;
    unsigned short* la = &Al[w * 1024];
    unsigned short* lb = &Bl[w * 1024];
    const int nk = K >> 5;
    for (int kt = 0; kt < nk; ++kt) {
        GLDS16(ga0, la);
        GLDS16(ga1, la + 512);
        GLDS16(gb0, lb);
        GLDS16(gb1, lb + 512);
        ga0 += 32; ga1 += 32; gb0 += 32; gb1 += 32;
        __syncthreads();
        bf16x8 af[4], bv[4];
#pragma unroll
        for (int i = 0; i < 4; i++) af[i] = *(const bf16x8*)&Al[(wr + i * 16 + lr) * 32 + ko];
#pragma unroll
        for (int i = 0; i < 4; i++) bv[i] = *(const bf16x8*)&Bl[(wc + i * 16 + lr) * 32 + ko];
#pragma unroll
        for (int i = 0; i < 4; i++)
#pragma unroll
            for (int j = 0; j < 4; j++)
                acc[i][j] = __builtin_amdgcn_mfma_f32_16x16x32_bf16(af[i], bv[j], acc[i][j], 0, 0, 0);
        __syncthreads();
    }
#pragma unroll
    for (int j = 0; j < 4; j++) {
        const int col = n0 + wc + j * 16 + lr;
        const float bvv = BIAS ? bias[col] : 0.0f;
#pragma unroll
        for (int i = 0; i < 4; i++) {
#pragma unroll
            for (int r = 0; r < 4; r++) {
                const int row = m0 + wr + i * 16 + (l >> 4) * 4 + r;
                float v = acc[i][j][r] + bvv;
                if (GELU_) v = 0.5f * v * (1.0f + erff(v * 0.7071067811865476f));
                if (RES) v += res[(size_t)row * N + col];
                if (OUTBF) ((unsigned short*)outp)[(size_t)row * N + col] = f2b(v);
                else       ((float*)outp)[(size_t)row * N + col] = v;
            }
        }
    }
}

// ---------------- 8-phase 256x256 GEMM (T1+T2+T3+T4+T5), bf16 out
// LDS (128KB): half-tile = [128 rows][64 k] bf16 linear (128B rows), chunk-XOR
// swizzle (round 7, verified 0 conflicts). ROUND-8: removed lgkmcnt(0) +
// sched_barrier(0) from phase prologue — the pin serialized LDS service and
// MFMA (measured 2270 cyc/phase vs ~1200 work). Compiler-emitted fine-grained
// lgkmcnt lets MFMA overlap remaining LDS reads (m97/m141 lesson). WAR safety:
// every read is consumed by an MFMA in its own phase (issue forces drain) and
// a barrier separates that MFMA from any later re-stage of the region.
#define WAITVM4() asm volatile("s_waitcnt vmcnt(4)" ::: "memory")
#define WAITVM0() asm volatile("s_waitcnt vmcnt(0)" ::: "memory")
#define WAITLG()  asm volatile("s_waitcnt lgkmcnt(0)" ::: "memory")
#define BAR() __builtin_amdgcn_s_barrier()

template <int S, int HM>
__device__ __forceinline__ void read_a(const unsigned short* LDSu, bf16x8 (&af)[8],
                                       int wr, int lr, int k0x, int k1x) {
    const unsigned short* pa = LDSu + S * 16384 + wr * 8192;
#pragma unroll
    for (int mi = 0; mi < 4; mi++) {
        const int row = HM * 64 + mi * 16 + lr;
        af[mi * 2 + 0] = *(const bf16x8*)&pa[row * 64 + k0x];
        af[mi * 2 + 1] = *(const bf16x8*)&pa[row * 64 + k1x];
    }
}
template <int S, int HN>
__device__ __forceinline__ void read_b(const unsigned short* LDSu, bf16x8 (&bf)[4],
                                       int wc, int lr, int k0x, int k1x) {
    const unsigned short* pb = LDSu + 32768 + S * 16384 + (wc >> 1) * 8192;
#pragma unroll
    for (int nj = 0; nj < 2; nj++) {
        const int row = (wc & 1) * 64 + HN * 32 + nj * 16 + lr;
        bf[nj * 2 + 0] = *(const bf16x8*)&pb[row * 64 + k0x];
        bf[nj * 2 + 1] = *(const bf16x8*)&pb[row * 64 + k1x];
    }
}
template <int HM, int HN>
__device__ __forceinline__ void quad(f32x4 (&acc)[8][4], const bf16x8 (&af)[8],
                                     const bf16x8 (&bf)[4]) {
    __builtin_amdgcn_s_setprio(1);
#pragma unroll
    for (int mi = 0; mi < 4; mi++)
#pragma unroll
        for (int nj = 0; nj < 2; nj++)
#pragma unroll
            for (int ks = 0; ks < 2; ks++)
                acc[HM * 4 + mi][HN * 2 + nj] = __builtin_amdgcn_mfma_f32_16x16x32_bf16(
                    af[mi * 2 + ks], bf[nj * 2 + ks], acc[HM * 4 + mi][HN * 2 + nj], 0, 0, 0);
    __builtin_amdgcn_s_setprio(0);
}

template <bool BIAS, bool GELU_>
__global__ __launch_bounds__(512, 2) void gemm8_k(const unsigned short* __restrict__ A,
                                                  const unsigned short* __restrict__ Bt,
                                                  const float* __restrict__ bias,
                                                  unsigned short* __restrict__ out,
                                                  int N, int K, int nbx) {
    extern __shared__ unsigned short LDSu[];  // 131072 B
    const int tid = threadIdx.x, w = tid >> 6, l = tid & 63;
    const int wr = w >> 2, wc = w & 3;
    const int lr = l & 15, lg = l >> 4;
    (void)nbx;
    // XCD-chunk mapping: 16 cols x 2 m-rows resident per XCD (round 6).
    const int id = blockIdx.x;
    const int x = id & 7, j = id >> 3;
    const int m0 = (2 * x + (j & 1)) * 256;
    const int n0 = (j >> 1) * 256;

    // read-side swizzle offsets (short units): k = (ks*32 + lg*8) ^ ((lr&7)<<3)
    const int swx = (lr & 7) << 3;
    const int k0x = (lg * 8) ^ swx;
    const int k1x = k0x ^ 32;

    // write-side pre-swizzled source: dest chunk tid holds global chunk swz(tid)
    const int cs = tid ^ ((tid >> 3) & 7);
    const int sr = cs >> 3, sc = (cs & 7) * 8;
    const unsigned short* a0row = A + (size_t)(m0 + sr) * K + sc;
    const unsigned short* a1row = A + (size_t)(m0 + 128 + sr) * K + sc;
    const unsigned short* b0row = Bt + (size_t)(n0 + sr) * K + sc;
    const unsigned short* b1row = Bt + (size_t)(n0 + 128 + sr) * K + sc;
    const size_t row64 = (size_t)64 * K;  // second gload covers rows 64-127 of the half

#define STAGE_A(S, H, ROW, KOFF) do { \
    GLDS16((ROW) + (KOFF),         LDSu + (S) * 16384 + (H) * 8192 + tid * 8); \
    GLDS16((ROW) + row64 + (KOFF), LDSu + (S) * 16384 + (H) * 8192 + 4096 + tid * 8); } while (0)
#define STAGE_B(S, H, ROW, KOFF) do { \
    GLDS16((ROW) + (KOFF),         LDSu + 32768 + (S) * 16384 + (H) * 8192 + tid * 8); \
    GLDS16((ROW) + row64 + (KOFF), LDSu + 32768 + (S) * 16384 + (H) * 8192 + 4096 + tid * 8); } while (0)

    f32x4 acc[8][4] = {};
    bf16x8 af[8], bf0[4], bf1[4];

    // prologue: tile0 all 4 halves + tile1 B-halves; wait tile0 landed (4 left in flight)
    STAGE_A(0, 0, a0row, 0);
    STAGE_A(0, 1, a1row, 0);
    STAGE_B(0, 0, b0row, 0);
    STAGE_B(0, 1, b1row, 0);
    STAGE_B(1, 0, b0row, 64);
    STAGE_B(1, 1, b1row, 64);
    WAITVM4();
    BAR();

    const int niter = K >> 7;  // 2 K-tiles of 64 per iteration
    for (int i = 0; i < niter; ++i) {
        const bool last = (i == niter - 1);
        const int k1 = (2 * i + 1) * 64, k2 = k1 + 64, k3 = k1 + 128;
        // ph1
        read_a<0, 0>(LDSu, af, wr, lr, k0x, k1x);
        read_b<0, 0>(LDSu, bf0, wc, lr, k0x, k1x);
        STAGE_A(1, 0, a0row, k1);
        BAR(); quad<0, 0>(acc, af, bf0); BAR();
        // ph2
        read_b<0, 1>(LDSu, bf1, wc, lr, k0x, k1x);
        STAGE_A(1, 1, a1row, k1);
        BAR(); quad<0, 1>(acc, af, bf1); BAR();
        // ph3
        read_a<0, 1>(LDSu, af, wr, lr, k0x, k1x);
        if (!last) STAGE_B(0, 0, b0row, k2);
        BAR(); quad<1, 1>(acc, af, bf1); BAR();
        // ph4
        if (!last) { STAGE_B(0, 1, b1row, k2); WAITVM4(); } else { WAITVM0(); }
        BAR(); quad<1, 0>(acc, af, bf0); BAR();
        // ph5 (slot1)
        read_a<1, 0>(LDSu, af, wr, lr, k0x, k1x);
        read_b<1, 0>(LDSu, bf0, wc, lr, k0x, k1x);
        if (!last) STAGE_A(0, 0, a0row, k2);
        BAR(); quad<0, 0>(acc, af, bf0); BAR();
        // ph6
        read_b<1, 1>(LDSu, bf1, wc, lr, k0x, k1x);
        if (!last) STAGE_A(0, 1, a1row, k2);
        BAR(); quad<0, 1>(acc, af, bf1); BAR();
        // ph7
        read_a<1, 1>(LDSu, af, wr, lr, k0x, k1x);
        if (!last) STAGE_B(1, 0, b0row, k3);
        BAR(); quad<1, 1>(acc, af, bf1); BAR();
        // ph8
        if (!last) { STAGE_B(1, 1, b1row, k3); WAITVM4(); }
        BAR(); quad<1, 0>(acc, af, bf0); BAR();
    }

    // epilogue: per-wave LDS bounce (16x68 f32, padded) -> full-line bf16 stores
    // FULLY UNROLLED: every acc index must be compile-time (rule #20).
    float* eb = (float*)&LDSu[(size_t)w * 2176];  // 4352 B per wave
    const int row16 = l >> 2, ch = l & 3;
    float4 bv[4];
    if (BIAS) {
#pragma unroll
        for (int q = 0; q < 4; q++)
            bv[q] = *(const float4*)&bias[n0 + wc * 64 + ch * 16 + q * 4];
    }
#pragma unroll
    for (int mi8 = 0; mi8 < 8; ++mi8) {
        WAITLG();  // prev pass ds_reads landed before overwrite
        __builtin_amdgcn_sched_barrier(0);
#pragma unroll
        for (int nj = 0; nj < 4; nj++)
#pragma unroll
            for (int rr = 0; rr < 4; rr++)
                eb[(lg * 4 + rr) * 68 + nj * 16 + lr] = acc[mi8][nj][rr];
        WAITLG();
        __builtin_amdgcn_sched_barrier(0);
        alignas(16) unsigned short tmp[16];
#pragma unroll
        for (int q = 0; q < 4; q++) {
            float4 v = *(const float4*)&eb[row16 * 68 + ch * 16 + q * 4];
            float e0 = v.x, e1 = v.y, e2 = v.z, e3 = v.w;
            if (BIAS) { e0 += bv[q].x; e1 += bv[q].y; e2 += bv[q].z; e3 += bv[q].w; }
            if (GELU_) {
                e0 = 0.5f * e0 * (1.0f + erff(e0 * 0.7071067811865476f));
                e1 = 0.5f * e1 * (1.0f + erff(e1 * 0.7071067811865476f));
                e2 = 0.5f * e2 * (1.0f + erff(e2 * 0.7071067811865476f));
                e3 = 0.5f * e3 * (1.0f + erff(e3 * 0.7071067811865476f));
            }
            tmp[q * 4 + 0] = f2b(e0); tmp[q * 4 + 1] = f2b(e1);
            tmp[q * 4 + 2] = f2b(e2); tmp[q * 4 + 3] = f2b(e3);
        }
        unsigned short* dst = out + (size_t)(m0 + wr * 128 + mi8 * 16 + row16) * N
                              + n0 + wc * 64 + ch * 16;
        *(uint4*)dst = *(const uint4*)tmp;
        *(uint4*)(dst + 8) = *(const uint4*)(tmp + 8);
    }
#undef STAGE_A
#undef STAGE_B
}

// ---------------- flash attention (causal), qkv bf16 [B*L][3*DM], out bf16 [B*L][DM]
__global__ __launch_bounds__(256) void flash_attn_k(const unsigned short* __restrict__ qkv,
                                                    unsigned short* __restrict__ out) {
    __shared__ unsigned short Kl[64 * 136];   // K tile [key][d], padded stride 136
    __shared__ unsigned short Vt[128 * 64];   // V tile transposed [d][key], XOR-swizzled
    __shared__ unsigned short Pl[4][16 * 72]; // per-wave P [qrow][key], padded
    const int tid = threadIdx.x, w = tid >> 6, l = tid & 63;
    const int bh = blockIdx.y, b = bh >> 4, h = bh & 15;
    const int lr = l & 15, lg = l >> 4;
    const float sc = 0.08838834764831845f;  // 1/sqrt(128)
    const int NT = LSEQ / 64;               // 32

#pragma unroll 1
    for (int pi = 0; pi < 2; ++pi) {
        const int qt = (pi == 0) ? (int)blockIdx.x : (NT - 1 - (int)blockIdx.x);
        const int qw = qt * 64 + w * 16;

        bf16x8 qf[4];
        {
            const unsigned short* qb = qkv + (size_t)(b * LSEQ + qw + lr) * (3 * DM) + h * HDIM + lg * 8;
#pragma unroll
            for (int kc = 0; kc < 4; kc++) qf[kc] = *(const bf16x8*)(qb + kc * 32);
        }
        f32x4 O[8] = {};
        float m_run[4] = {-1e30f, -1e30f, -1e30f, -1e30f};
        float l_run[4] = {};

        for (int kt = 0; kt <= qt; ++kt) {
            const int k0 = kt * 64;
#pragma unroll
            for (int i = 0; i < 4; i++) {
                const int seg = i * 256 + tid;       // 0..1023
                const int row = seg >> 4;            // 0..63
                const int c8  = (seg & 15) * 8;      // 0..120
                const unsigned short* src = qkv + (size_t)(b * LSEQ + k0 + row) * (3 * DM) + DM + h * HDIM + c8;
                *(uint4*)&Kl[row * 136 + c8] = *(const uint4*)src;
                unsigned short tmp[8];
                *(uint4*)tmp = *(const uint4*)(src + DM);
#pragma unroll
                for (int j = 0; j < 8; j++) {
                    const int d = c8 + j;
                    Vt[d * 64 + (row ^ ((((d >> 3) ^ d) & 7) << 3))] = tmp[j];
                }
            }
            __syncthreads();
            f32x4 S[4] = {};
#pragma unroll
            for (int st = 0; st < 4; ++st)
#pragma unroll
                for (int kc = 0; kc < 4; kc++) {
                    bf16x8 kb = *(const bf16x8*)&Kl[(st * 16 + lr) * 136 + kc * 32 + lg * 8];
                    S[st] = __builtin_amdgcn_mfma_f32_16x16x32_bf16(qf[kc], kb, S[st], 0, 0, 0);
                }
            const bool lastt = (kt == qt);
#pragma unroll
            for (int rq = 0; rq < 4; rq++) {
                const int row = qw + lg * 4 + rq;
                float s0 = S[0][rq] * sc, s1 = S[1][rq] * sc, s2 = S[2][rq] * sc, s3 = S[3][rq] * sc;
                if (lastt) {
                    if (k0 +  0 + lr > row) s0 = -1e30f;
                    if (k0 + 16 + lr > row) s1 = -1e30f;
                    if (k0 + 32 + lr > row) s2 = -1e30f;
                    if (k0 + 48 + lr > row) s3 = -1e30f;
                }
                float mt = fmaxf(fmaxf(s0, s1), fmaxf(s2, s3));
                mt = fmaxf(mt, __shfl_xor(mt, 1));
                mt = fmaxf(mt, __shfl_xor(mt, 2));
                mt = fmaxf(mt, __shfl_xor(mt, 4));
                mt = fmaxf(mt, __shfl_xor(mt, 8));
                const float mn = fmaxf(m_run[rq], mt);
                const float al = __expf(m_run[rq] - mn);
                m_run[rq] = mn;
                float p0 = __expf(s0 - mn), p1 = __expf(s1 - mn), p2 = __expf(s2 - mn), p3 = __expf(s3 - mn);
                float ts = p0 + p1 + p2 + p3;
                ts += __shfl_xor(ts, 1);
                ts += __shfl_xor(ts, 2);
                ts += __shfl_xor(ts, 4);
                ts += __shfl_xor(ts, 8);
                l_run[rq] = l_run[rq] * al + ts;
#pragma unroll
                for (int c = 0; c < 8; c++) O[c][rq] *= al;
                unsigned short* pr = &Pl[w][(lg * 4 + rq) * 72 + lr];
                pr[0] = f2b(p0); pr[16] = f2b(p1); pr[32] = f2b(p2); pr[48] = f2b(p3);
            }
#pragma unroll
            for (int ks = 0; ks < 2; ++ks) {
                bf16x8 pa = *(const bf16x8*)&Pl[w][lr * 72 + ks * 32 + lg * 8];
#pragma unroll
                for (int c = 0; c < 8; c++) {
                    const int d = c * 16 + lr;
                    bf16x8 vb = *(const bf16x8*)&Vt[d * 64 + ((ks * 32 + lg * 8) ^ ((((d >> 3) ^ d) & 7) << 3))];
                    O[c] = __builtin_amdgcn_mfma_f32_16x16x32_bf16(pa, vb, O[c], 0, 0, 0);
                }
            }
            __syncthreads();
        }
#pragma unroll
        for (int rq = 0; rq < 4; rq++) {
            const float inv = 1.0f / l_run[rq];
            const size_t ro = (size_t)(b * LSEQ + qw + lg * 4 + rq) * DM + h * HDIM;
#pragma unroll
            for (int c = 0; c < 8; c++) out[ro + c * 16 + lr] = f2b(O[c][rq] * inv);
        }
    }
}

extern "C" void kernel_launch(void* const* d_in, const int* in_sizes, int n_in,
                              void* d_out, int out_size, void* d_ws, size_t ws_size,
                              hipStream_t stream) {
    const float* x     = (const float*)d_in[0];
    const float* w_qkv = (const float*)d_in[2];
    const float* w_o   = (const float*)d_in[3];
    const float* g1    = (const float*)d_in[4];
    const float* bl1   = (const float*)d_in[5];
    const float* g2    = (const float*)d_in[6];
    const float* bl2   = (const float*)d_in[7];
    const float* w1    = (const float*)d_in[8];
    const float* b1    = (const float*)d_in[9];
    const float* w2    = (const float*)d_in[10];
    const float* b2    = (const float*)d_in[11];
    float* out = (float*)d_out;

    unsigned char* p = (unsigned char*)d_ws;
    unsigned short* wqkvT = (unsigned short*)p; p += (size_t)3 * DM * DM * 2;
    unsigned short* woT   = (unsigned short*)p; p += (size_t)DM * DM * 2;
    unsigned short* w1T   = (unsigned short*)p; p += (size_t)DFF * DM * 2;
    unsigned short* w2T   = (unsigned short*)p; p += (size_t)DM * DFF * 2;
    unsigned short* hbuf  = (unsigned short*)p; p += (size_t)NB * LSEQ * DM * 2;
    unsigned short* big   = (unsigned short*)p; p += (size_t)NB * LSEQ * DFF * 2;
    float* x2 = out;  // x2 lives in d_out; final GEMM reads it as res then overwrites

    const int R = NB * LSEQ;  // 4096
    dim3 tb(32, 8);
    transpose_bf16<<<dim3(3 * DM / 32, DM / 32), tb, 0, stream>>>(w_qkv, wqkvT, DM, 3 * DM);
    transpose_bf16<<<dim3(DM / 32, DM / 32), tb, 0, stream>>>(w_o, woT, DM, DM);
    transpose_bf16<<<dim3(DFF / 32, DM / 32), tb, 0, stream>>>(w1, w1T, DM, DFF);
    transpose_bf16<<<dim3(DM / 32, DFF / 32), tb, 0, stream>>>(w2, w2T, DFF, DM);

    ln_k<<<R, 256, 0, stream>>>(x, g1, bl1, hbuf);
    gemm8_k<false, false><<<(R / 256) * (3 * DM / 256), 512, 131072, stream>>>(
        hbuf, wqkvT, nullptr, big, 3 * DM, DM, 3 * DM / 256);
    flash_attn_k<<<dim3(LSEQ / 128, NB * NH), 256, 0, stream>>>(big, hbuf);
    gemm_k<false, false, true, false><<<dim3(DM / 128, R / 128), 256, 0, stream>>>(
        hbuf, woT, nullptr, x, x2, R, DM, DM);
    ln_k<<<R, 256, 0, stream>>>(x2, g2, bl2, hbuf);
    gemm8_k<true, true><<<(R / 256) * (DFF / 256), 512, 131072, stream>>>(
        hbuf, w1T, b1, big, DFF, DM, DFF / 256);
    gemm_k<true, false, true, false><<<dim3(DM / 128, R / 128), 256, 0, stream>>>(
        big, w2T, b2, x2, out, R, DM, DFF);
}

// Round 9
// 806.209 us; speedup vs baseline: 1.0066x; 1.0066x over previous
//
#include <hip/hip_runtime.h>
#include <hip/hip_bf16.h>

#define DM   2048
#define LSEQ 2048
#define NB   2
#define NH   16
#define HDIM 128
#define DFF  8192

typedef __attribute__((ext_vector_type(8))) short bf16x8;
typedef __attribute__((ext_vector_type(4))) float f32x4;

typedef __attribute__((address_space(1))) void gvoid;
typedef __attribute__((address_space(3))) void lvoid;
#define GLDS16(g, s) __builtin_amdgcn_global_load_lds((const gvoid*)(g), (lvoid*)(s), 16, 0, 0)

__device__ __forceinline__ unsigned short f2b(float f) {
    __hip_bfloat16 h = __float2bfloat16(f);
    return *reinterpret_cast<unsigned short*>(&h);
}

// ---------------- transpose + fp32->bf16 convert: in[R][C] f32 -> out[C][R] bf16
__global__ __launch_bounds__(256) void transpose_bf16(const float* __restrict__ in,
                                                      unsigned short* __restrict__ out,
                                                      int R, int C) {
    __shared__ float t[32][33];
    const int c0 = blockIdx.x * 32, r0 = blockIdx.y * 32;
    const int tx = threadIdx.x, ty = threadIdx.y;  // block (32,8)
#pragma unroll
    for (int i = 0; i < 4; i++)
        t[ty + 8 * i][tx] = in[(size_t)(r0 + ty + 8 * i) * C + c0 + tx];
    __syncthreads();
#pragma unroll
    for (int i = 0; i < 4; i++)
        out[(size_t)(c0 + ty + 8 * i) * R + r0 + tx] = f2b(t[tx][ty + 8 * i]);
}

// ---------------- LayerNorm: x[row][2048] f32 -> out bf16
__global__ __launch_bounds__(256) void ln_k(const float* __restrict__ x,
                                            const float* __restrict__ g,
                                            const float* __restrict__ bta,
                                            unsigned short* __restrict__ out) {
    const int row = blockIdx.x, tid = threadIdx.x;
    const float* xr = x + (size_t)row * DM;
    float4 v0 = *(const float4*)&xr[tid * 4];
    float4 v1 = *(const float4*)&xr[1024 + tid * 4];
    float s  = v0.x + v0.y + v0.z + v0.w + v1.x + v1.y + v1.z + v1.w;
    float ss = v0.x * v0.x + v0.y * v0.y + v0.z * v0.z + v0.w * v0.w
             + v1.x * v1.x + v1.y * v1.y + v1.z * v1.z + v1.w * v1.w;
#pragma unroll
    for (int o = 32; o; o >>= 1) { s += __shfl_down(s, o); ss += __shfl_down(ss, o); }
    __shared__ float red[8];
    const int w = tid >> 6, l = tid & 63;
    if (l == 0) { red[w] = s; red[4 + w] = ss; }
    __syncthreads();
    s  = red[0] + red[1] + red[2] + red[3];
    ss = red[4] + red[5] + red[6] + red[7];
    const float mu  = s * (1.0f / DM);
    const float var = ss * (1.0f / DM) - mu * mu;
    const float rst = rsqrtf(var + 1e-5f);
    float4 g0 = *(const float4*)&g[tid * 4];
    float4 b0 = *(const float4*)&bta[tid * 4];
    float4 g1 = *(const float4*)&g[1024 + tid * 4];
    float4 b1 = *(const float4*)&bta[1024 + tid * 4];
    ushort4 o0, o1;
    o0.x = f2b((v0.x - mu) * rst * g0.x + b0.x);
    o0.y = f2b((v0.y - mu) * rst * g0.y + b0.y);
    o0.z = f2b((v0.z - mu) * rst * g0.z + b0.z);
    o0.w = f2b((v0.w - mu) * rst * g0.w + b0.w);
    o1.x = f2b((v1.x - mu) * rst * g1.x + b1.x);
    o1.y = f2b((v1.y - mu) * rst * g1.y + b1.y);
    o1.z = f2b((v1.z - mu) * rst * g1.z + b1.z);
    o1.w = f2b((v1.w - mu) * rst * g1.w + b1.w);
    *(ushort4*)&out[(size_t)row * DM + tid * 4] = o0;
    *(ushort4*)&out[(size_t)row * DM + 1024 + tid * 4] = o1;
}

// ---------------- m97-style GEMM (WO, MLP2; both launched at grid (16,32))
// XCD column-major remap: resident 32 blocks/XCD = 4 m-rows x 8 n-cols.
template <bool BIAS, bool GELU_, bool RES, bool OUTBF>
__global__ __launch_bounds__(256) void gemm_k(const unsigned short* __restrict__ A,
                                              const unsigned short* __restrict__ Bt,
                                              const float* __restrict__ bias,
                                              const float* __restrict__ res,
                                              void* __restrict__ outp,
                                              int M, int N, int K) {
    __shared__ unsigned short Al[128 * 32];
    __shared__ unsigned short Bl[128 * 32];
    const int tid = threadIdx.x, w = tid >> 6, l = tid & 63;
    int bx = blockIdx.x, by = blockIdx.y;
    if (gridDim.x == 16 && gridDim.y == 32) {  // WO / MLP2 shape
        const int flat = by * 16 + bx;         // dispatch order (x fastest)
        const int xx = flat & 7, jj = flat >> 3;
        by = 4 * xx + (jj & 3);                // m-row
        bx = jj >> 2;                          // n-col
    }
    const int n0 = bx * 128, m0 = by * 128;
    const int wr = (w >> 1) * 64, wc = (w & 1) * 64;
    const int lr = l & 15, ko = (l >> 4) * 8;
    f32x4 acc[4][4] = {};

    const int srow = w * 32 + (l >> 2);
    const int skk  = (l & 3) * 8;
    const unsigned short* ga0 = A + (size_t)(m0 + srow) * K + skk;
    const unsigned short* ga1 = ga0 + (size_t)16 * K;
    const unsigned short* gb0 = Bt + (size_t)(n0 + srow) * K + skk;
    const unsigned short* gb1 = gb0 + (size_t)16 * K;
    unsigned short* la = &Al[w * 1024];
    unsigned short* lb = &Bl[w * 1024];
    const int nk = K >> 5;
    for (int kt = 0; kt < nk; ++kt) {
        GLDS16(ga0, la);
        GLDS16(ga1, la + 512);
        GLDS16(gb0, lb);
        GLDS16(gb1, lb + 512);
        ga0 += 32; ga1 += 32; gb0 += 32; gb1 += 32;
        __syncthreads();
        bf16x8 af[4], bv[4];
#pragma unroll
        for (int i = 0; i < 4; i++) af[i] = *(const bf16x8*)&Al[(wr + i * 16 + lr) * 32 + ko];
#pragma unroll
        for (int i = 0; i < 4; i++) bv[i] = *(const bf16x8*)&Bl[(wc + i * 16 + lr) * 32 + ko];
#pragma unroll
        for (int i = 0; i < 4; i++)
#pragma unroll
            for (int j = 0; j < 4; j++)
                acc[i][j] = __builtin_amdgcn_mfma_f32_16x16x32_bf16(af[i], bv[j], acc[i][j], 0, 0, 0);
        __syncthreads();
    }
#pragma unroll
    for (int j = 0; j < 4; j++) {
        const int col = n0 + wc + j * 16 + lr;
        const float bvv = BIAS ? bias[col] : 0.0f;
#pragma unroll
        for (int i = 0; i < 4; i++) {
#pragma unroll
            for (int r = 0; r < 4; r++) {
                const int row = m0 + wr + i * 16 + (l >> 4) * 4 + r;
                float v = acc[i][j][r] + bvv;
                if (GELU_) v = 0.5f * v * (1.0f + erff(v * 0.7071067811865476f));
                if (RES) v += res[(size_t)row * N + col];
                if (OUTBF) ((unsigned short*)outp)[(size_t)row * N + col] = f2b(v);
                else       ((float*)outp)[(size_t)row * N + col] = v;
            }
        }
    }
}

// ---------------- 4-phase 256x256 GEMM (T1+T2+T4+T5), bf16 out
// ROUND-9: merged 8 phases -> 4 (32-MFMA clusters, 8 barriers/iter instead of
// 16) to test the barrier-lockstep-overhead theory: rounds 6-8 showed no
// saturated pipe (MFMA 24%, VALU 23%, conflicts 0, HBM 11%) at 2270 cyc/phase
// vs ~1100 of work — dead time attributed to 16 lockstep barrier crossings.
// vmcnt ledger (4 loads/phase-stage): prologue leaves s1.B(4) outstanding;
// ph2 WAITVM4 drains {prev s1.B, ph1 s1.A} -> ph3's s1 reads safe;
// ph4 WAITVM4 drains {ph2 s0.B, ph3 s0.A} -> next ph1's s0 reads safe.
// Overwrite-release: each re-staged region's reads were MFMA-consumed >=1
// barrier before the stage issues. Last iter: ph2 degrades to WAITVM0.
#define WAITVM4() asm volatile("s_waitcnt vmcnt(4)" ::: "memory")
#define WAITVM0() asm volatile("s_waitcnt vmcnt(0)" ::: "memory")
#define WAITLG()  asm volatile("s_waitcnt lgkmcnt(0)" ::: "memory")
#define BAR() __builtin_amdgcn_s_barrier()

template <int S, int HM>
__device__ __forceinline__ void read_a(const unsigned short* LDSu, bf16x8 (&af)[8],
                                       int wr, int lr, int k0x, int k1x) {
    const unsigned short* pa = LDSu + S * 16384 + wr * 8192;
#pragma unroll
    for (int mi = 0; mi < 4; mi++) {
        const int row = HM * 64 + mi * 16 + lr;
        af[mi * 2 + 0] = *(const bf16x8*)&pa[row * 64 + k0x];
        af[mi * 2 + 1] = *(const bf16x8*)&pa[row * 64 + k1x];
    }
}
template <int S, int HN>
__device__ __forceinline__ void read_b(const unsigned short* LDSu, bf16x8 (&bf)[4],
                                       int wc, int lr, int k0x, int k1x) {
    const unsigned short* pb = LDSu + 32768 + S * 16384 + (wc >> 1) * 8192;
#pragma unroll
    for (int nj = 0; nj < 2; nj++) {
        const int row = (wc & 1) * 64 + HN * 32 + nj * 16 + lr;
        bf[nj * 2 + 0] = *(const bf16x8*)&pb[row * 64 + k0x];
        bf[nj * 2 + 1] = *(const bf16x8*)&pb[row * 64 + k1x];
    }
}
template <int HM, int HN>
__device__ __forceinline__ void quad(f32x4 (&acc)[8][4], const bf16x8 (&af)[8],
                                     const bf16x8 (&bf)[4]) {
#pragma unroll
    for (int mi = 0; mi < 4; mi++)
#pragma unroll
        for (int nj = 0; nj < 2; nj++)
#pragma unroll
            for (int ks = 0; ks < 2; ks++)
                acc[HM * 4 + mi][HN * 2 + nj] = __builtin_amdgcn_mfma_f32_16x16x32_bf16(
                    af[mi * 2 + ks], bf[nj * 2 + ks], acc[HM * 4 + mi][HN * 2 + nj], 0, 0, 0);
}

template <bool BIAS, bool GELU_>
__global__ __launch_bounds__(512, 2) void gemm8_k(const unsigned short* __restrict__ A,
                                                  const unsigned short* __restrict__ Bt,
                                                  const float* __restrict__ bias,
                                                  unsigned short* __restrict__ out,
                                                  int N, int K, int nbx) {
    extern __shared__ unsigned short LDSu[];  // 131072 B
    const int tid = threadIdx.x, w = tid >> 6, l = tid & 63;
    const int wr = w >> 2, wc = w & 3;
    const int lr = l & 15, lg = l >> 4;
    (void)nbx;
    // XCD-chunk mapping: 16 cols x 2 m-rows resident per XCD (round 6).
    const int id = blockIdx.x;
    const int x = id & 7, j = id >> 3;
    const int m0 = (2 * x + (j & 1)) * 256;
    const int n0 = (j >> 1) * 256;

    // read-side swizzle offsets (short units): k = (ks*32 + lg*8) ^ ((lr&7)<<3)
    const int swx = (lr & 7) << 3;
    const int k0x = (lg * 8) ^ swx;
    const int k1x = k0x ^ 32;

    // write-side pre-swizzled source: dest chunk tid holds global chunk swz(tid)
    const int cs = tid ^ ((tid >> 3) & 7);
    const int sr = cs >> 3, sc = (cs & 7) * 8;
    const unsigned short* a0row = A + (size_t)(m0 + sr) * K + sc;
    const unsigned short* a1row = A + (size_t)(m0 + 128 + sr) * K + sc;
    const unsigned short* b0row = Bt + (size_t)(n0 + sr) * K + sc;
    const unsigned short* b1row = Bt + (size_t)(n0 + 128 + sr) * K + sc;
    const size_t row64 = (size_t)64 * K;  // second gload covers rows 64-127 of the half

#define STAGE_A(S, H, ROW, KOFF) do { \
    GLDS16((ROW) + (KOFF),         LDSu + (S) * 16384 + (H) * 8192 + tid * 8); \
    GLDS16((ROW) + row64 + (KOFF), LDSu + (S) * 16384 + (H) * 8192 + 4096 + tid * 8); } while (0)
#define STAGE_B(S, H, ROW, KOFF) do { \
    GLDS16((ROW) + (KOFF),         LDSu + 32768 + (S) * 16384 + (H) * 8192 + tid * 8); \
    GLDS16((ROW) + row64 + (KOFF), LDSu + 32768 + (S) * 16384 + (H) * 8192 + 4096 + tid * 8); } while (0)

    f32x4 acc[8][4] = {};
    bf16x8 af[8], bf0[4], bf1[4];

    // prologue: tile0 all 4 halves + tile1 B-halves; wait tile0 landed (4 left in flight)
    STAGE_A(0, 0, a0row, 0);
    STAGE_A(0, 1, a1row, 0);
    STAGE_B(0, 0, b0row, 0);
    STAGE_B(0, 1, b1row, 0);
    STAGE_B(1, 0, b0row, 64);
    STAGE_B(1, 1, b1row, 64);
    WAITVM4();
    BAR();

    const int niter = K >> 7;  // 2 K-tiles of 64 per iteration
    for (int i = 0; i < niter; ++i) {
        const bool last = (i == niter - 1);
        const int k1 = (2 * i + 1) * 64, k2 = k1 + 64, k3 = k1 + 128;
        // ph1: read s0 {A0, B0, B1}; stage s1.A (tile 2i+1)
        read_a<0, 0>(LDSu, af, wr, lr, k0x, k1x);
        read_b<0, 0>(LDSu, bf0, wc, lr, k0x, k1x);
        read_b<0, 1>(LDSu, bf1, wc, lr, k0x, k1x);
        STAGE_A(1, 0, a0row, k1);
        STAGE_A(1, 1, a1row, k1);
        BAR();
        __builtin_amdgcn_s_setprio(1);
        quad<0, 0>(acc, af, bf0);
        quad<0, 1>(acc, af, bf1);
        __builtin_amdgcn_s_setprio(0);
        BAR();
        // ph2: read s0 {A1}; stage s0.B (tile 2i+2); drain for ph3's s1 reads
        read_a<0, 1>(LDSu, af, wr, lr, k0x, k1x);
        if (!last) {
            STAGE_B(0, 0, b0row, k2);
            STAGE_B(0, 1, b1row, k2);
            WAITVM4();
        } else {
            WAITVM0();
        }
        BAR();
        __builtin_amdgcn_s_setprio(1);
        quad<1, 1>(acc, af, bf1);
        quad<1, 0>(acc, af, bf0);
        __builtin_amdgcn_s_setprio(0);
        BAR();
        // ph3: read s1 {A0, B0, B1}; stage s0.A (tile 2i+2)
        read_a<1, 0>(LDSu, af, wr, lr, k0x, k1x);
        read_b<1, 0>(LDSu, bf0, wc, lr, k0x, k1x);
        read_b<1, 1>(LDSu, bf1, wc, lr, k0x, k1x);
        if (!last) {
            STAGE_A(0, 0, a0row, k2);
            STAGE_A(0, 1, a1row, k2);
        }
        BAR();
        __builtin_amdgcn_s_setprio(1);
        quad<0, 0>(acc, af, bf0);
        quad<0, 1>(acc, af, bf1);
        __builtin_amdgcn_s_setprio(0);
        BAR();
        // ph4: read s1 {A1}; stage s1.B (tile 2i+3); drain for next ph1's s0 reads
        read_a<1, 1>(LDSu, af, wr, lr, k0x, k1x);
        if (!last) {
            STAGE_B(1, 0, b0row, k3);
            STAGE_B(1, 1, b1row, k3);
            WAITVM4();
        }
        BAR();
        __builtin_amdgcn_s_setprio(1);
        quad<1, 1>(acc, af, bf1);
        quad<1, 0>(acc, af, bf0);
        __builtin_amdgcn_s_setprio(0);
        BAR();
    }

    // epilogue: per-wave LDS bounce (16x68 f32, padded) -> full-line bf16 stores
    // FULLY UNROLLED: every acc index must be compile-time (rule #20).
    float* eb = (float*)&LDSu[(size_t)w * 2176];  // 4352 B per wave
    const int row16 = l >> 2, ch = l & 3;
    float4 bv[4];
    if (BIAS) {
#pragma unroll
        for (int q = 0; q < 4; q++)
            bv[q] = *(const float4*)&bias[n0 + wc * 64 + ch * 16 + q * 4];
    }
#pragma unroll
    for (int mi8 = 0; mi8 < 8; ++mi8) {
        WAITLG();  // prev pass ds_reads landed before overwrite
        __builtin_amdgcn_sched_barrier(0);
#pragma unroll
        for (int nj = 0; nj < 4; nj++)
#pragma unroll
            for (int rr = 0; rr < 4; rr++)
                eb[(lg * 4 + rr) * 68 + nj * 16 + lr] = acc[mi8][nj][rr];
        WAITLG();
        __builtin_amdgcn_sched_barrier(0);
        alignas(16) unsigned short tmp[16];
#pragma unroll
        for (int q = 0; q < 4; q++) {
            float4 v = *(const float4*)&eb[row16 * 68 + ch * 16 + q * 4];
            float e0 = v.x, e1 = v.y, e2 = v.z, e3 = v.w;
            if (BIAS) { e0 += bv[q].x; e1 += bv[q].y; e2 += bv[q].z; e3 += bv[q].w; }
            if (GELU_) {
                e0 = 0.5f * e0 * (1.0f + erff(e0 * 0.7071067811865476f));
                e1 = 0.5f * e1 * (1.0f + erff(e1 * 0.7071067811865476f));
                e2 = 0.5f * e2 * (1.0f + erff(e2 * 0.7071067811865476f));
                e3 = 0.5f * e3 * (1.0f + erff(e3 * 0.7071067811865476f));
            }
            tmp[q * 4 + 0] = f2b(e0); tmp[q * 4 + 1] = f2b(e1);
            tmp[q * 4 + 2] = f2b(e2); tmp[q * 4 + 3] = f2b(e3);
        }
        unsigned short* dst = out + (size_t)(m0 + wr * 128 + mi8 * 16 + row16) * N
                              + n0 + wc * 64 + ch * 16;
        *(uint4*)dst = *(const uint4*)tmp;
        *(uint4*)(dst + 8) = *(const uint4*)(tmp + 8);
    }
#undef STAGE_A
#undef STAGE_B
}

// ---------------- flash attention (causal), qkv bf16 [B*L][3*DM], out bf16 [B*L][DM]
__global__ __launch_bounds__(256) void flash_attn_k(const unsigned short* __restrict__ qkv,
                                                    unsigned short* __restrict__ out) {
    __shared__ unsigned short Kl[64 * 136];   // K tile [key][d], padded stride 136
    __shared__ unsigned short Vt[128 * 64];   // V tile transposed [d][key], XOR-swizzled
    __shared__ unsigned short Pl[4][16 * 72]; // per-wave P [qrow][key], padded
    const int tid = threadIdx.x, w = tid >> 6, l = tid & 63;
    const int bh = blockIdx.y, b = bh >> 4, h = bh & 15;
    const int lr = l & 15, lg = l >> 4;
    const float sc = 0.08838834764831845f;  // 1/sqrt(128)
    const int NT = LSEQ / 64;               // 32

#pragma unroll 1
    for (int pi = 0; pi < 2; ++pi) {
        const int qt = (pi == 0) ? (int)blockIdx.x : (NT - 1 - (int)blockIdx.x);
        const int qw = qt * 64 + w * 16;

        bf16x8 qf[4];
        {
            const unsigned short* qb = qkv + (size_t)(b * LSEQ + qw + lr) * (3 * DM) + h * HDIM + lg * 8;
#pragma unroll
            for (int kc = 0; kc < 4; kc++) qf[kc] = *(const bf16x8*)(qb + kc * 32);
        }
        f32x4 O[8] = {};
        float m_run[4] = {-1e30f, -1e30f, -1e30f, -1e30f};
        float l_run[4] = {};

        for (int kt = 0; kt <= qt; ++kt) {
            const int k0 = kt * 64;
#pragma unroll
            for (int i = 0; i < 4; i++) {
                const int seg = i * 256 + tid;       // 0..1023
                const int row = seg >> 4;            // 0..63
                const int c8  = (seg & 15) * 8;      // 0..120
                const unsigned short* src = qkv + (size_t)(b * LSEQ + k0 + row) * (3 * DM) + DM + h * HDIM + c8;
                *(uint4*)&Kl[row * 136 + c8] = *(const uint4*)src;
                unsigned short tmp[8];
                *(uint4*)tmp = *(const uint4*)(src + DM);
#pragma unroll
                for (int j = 0; j < 8; j++) {
                    const int d = c8 + j;
                    Vt[d * 64 + (row ^ ((((d >> 3) ^ d) & 7) << 3))] = tmp[j];
                }
            }
            __syncthreads();
            f32x4 S[4] = {};
#pragma unroll
            for (int st = 0; st < 4; ++st)
#pragma unroll
                for (int kc = 0; kc < 4; kc++) {
                    bf16x8 kb = *(const bf16x8*)&Kl[(st * 16 + lr) * 136 + kc * 32 + lg * 8];
                    S[st] = __builtin_amdgcn_mfma_f32_16x16x32_bf16(qf[kc], kb, S[st], 0, 0, 0);
                }
            const bool lastt = (kt == qt);
#pragma unroll
            for (int rq = 0; rq < 4; rq++) {
                const int row = qw + lg * 4 + rq;
                float s0 = S[0][rq] * sc, s1 = S[1][rq] * sc, s2 = S[2][rq] * sc, s3 = S[3][rq] * sc;
                if (lastt) {
                    if (k0 +  0 + lr > row) s0 = -1e30f;
                    if (k0 + 16 + lr > row) s1 = -1e30f;
                    if (k0 + 32 + lr > row) s2 = -1e30f;
                    if (k0 + 48 + lr > row) s3 = -1e30f;
                }
                float mt = fmaxf(fmaxf(s0, s1), fmaxf(s2, s3));
                mt = fmaxf(mt, __shfl_xor(mt, 1));
                mt = fmaxf(mt, __shfl_xor(mt, 2));
                mt = fmaxf(mt, __shfl_xor(mt, 4));
                mt = fmaxf(mt, __shfl_xor(mt, 8));
                const float mn = fmaxf(m_run[rq], mt);
                const float al = __expf(m_run[rq] - mn);
                m_run[rq] = mn;
                float p0 = __expf(s0 - mn), p1 = __expf(s1 - mn), p2 = __expf(s2 - mn), p3 = __expf(s3 - mn);
                float ts = p0 + p1 + p2 + p3;
                ts += __shfl_xor(ts, 1);
                ts += __shfl_xor(ts, 2);
                ts += __shfl_xor(ts, 4);
                ts += __shfl_xor(ts, 8);
                l_run[rq] = l_run[rq] * al + ts;
#pragma unroll
                for (int c = 0; c < 8; c++) O[c][rq] *= al;
                unsigned short* pr = &Pl[w][(lg * 4 + rq) * 72 + lr];
                pr[0] = f2b(p0); pr[16] = f2b(p1); pr[32] = f2b(p2); pr[48] = f2b(p3);
            }
#pragma unroll
            for (int ks = 0; ks < 2; ++ks) {
                bf16x8 pa = *(const bf16x8*)&Pl[w][lr * 72 + ks * 32 + lg * 8];
#pragma unroll
                for (int c = 0; c < 8; c++) {
                    const int d = c * 16 + lr;
                    bf16x8 vb = *(const bf16x8*)&Vt[d * 64 + ((ks * 32 + lg * 8) ^ ((((d >> 3) ^ d) & 7) << 3))];
                    O[c] = __builtin_amdgcn_mfma_f32_16x16x32_bf16(pa, vb, O[c], 0, 0, 0);
                }
            }
            __syncthreads();
        }
#pragma unroll
        for (int rq = 0; rq < 4; rq++) {
            const float inv = 1.0f / l_run[rq];
            const size_t ro = (size_t)(b * LSEQ + qw + lg * 4 + rq) * DM + h * HDIM;
#pragma unroll
            for (int c = 0; c < 8; c++) out[ro + c * 16 + lr] = f2b(O[c][rq] * inv);
        }
    }
}

extern "C" void kernel_launch(void* const* d_in, const int* in_sizes, int n_in,
                              void* d_out, int out_size, void* d_ws, size_t ws_size,
                              hipStream_t stream) {
    const float* x     = (const float*)d_in[0];
    const float* w_qkv = (const float*)d_in[2];
    const float* w_o   = (const float*)d_in[3];
    const float* g1    = (const float*)d_in[4];
    const float* bl1   = (const float*)d_in[5];
    const float* g2    = (const float*)d_in[6];
    const float* bl2   = (const float*)d_in[7];
    const float* w1    = (const float*)d_in[8];
    const float* b1    = (const float*)d_in[9];
    const float* w2    = (const float*)d_in[10];
    const float* b2    = (const float*)d_in[11];
    float* out = (float*)d_out;

    unsigned char* p = (unsigned char*)d_ws;
    unsigned short* wqkvT = (unsigned short*)p; p += (size_t)3 * DM * DM * 2;
    unsigned short* woT   = (unsigned short*)p; p += (size_t)DM * DM * 2;
    unsigned short* w1T   = (unsigned short*)p; p += (size_t)DFF * DM * 2;
    unsigned short* w2T   = (unsigned short*)p; p += (size_t)DM * DFF * 2;
    unsigned short* hbuf  = (unsigned short*)p; p += (size_t)NB * LSEQ * DM * 2;
    unsigned short* big   = (unsigned short*)p; p += (size_t)NB * LSEQ * DFF * 2;
    float* x2 = out;  // x2 lives in d_out; final GEMM reads it as res then overwrites

    const int R = NB * LSEQ;  // 4096
    dim3 tb(32, 8);
    transpose_bf16<<<dim3(3 * DM / 32, DM / 32), tb, 0, stream>>>(w_qkv, wqkvT, DM, 3 * DM);
    transpose_bf16<<<dim3(DM / 32, DM / 32), tb, 0, stream>>>(w_o, woT, DM, DM);
    transpose_bf16<<<dim3(DFF / 32, DM / 32), tb, 0, stream>>>(w1, w1T, DM, DFF);
    transpose_bf16<<<dim3(DM / 32, DFF / 32), tb, 0, stream>>>(w2, w2T, DFF, DM);

    ln_k<<<R, 256, 0, stream>>>(x, g1, bl1, hbuf);
    gemm8_k<false, false><<<(R / 256) * (3 * DM / 256), 512, 131072, stream>>>(
        hbuf, wqkvT, nullptr, big, 3 * DM, DM, 3 * DM / 256);
    flash_attn_k<<<dim3(LSEQ / 128, NB * NH), 256, 0, stream>>>(big, hbuf);
    gemm_k<false, false, true, false><<<dim3(DM / 128, R / 128), 256, 0, stream>>>(
        hbuf, woT, nullptr, x, x2, R, DM, DM);
    ln_k<<<R, 256, 0, stream>>>(x2, g2, bl2, hbuf);
    gemm8_k<true, true><<<(R / 256) * (DFF / 256), 512, 131072, stream>>>(
        hbuf, w1T, b1, big, DFF, DM, DFF / 256);
    gemm_k<true, false, true, false><<<dim3(DM / 128, R / 128), 256, 0, stream>>>(
        big, w2T, b2, x2, out, R, DM, DFF);
}